// Round 5
// baseline (1368.035 us; speedup 1.0000x reference)
//
#include <hip/hip_runtime.h>
#include <stdint.h>

#define N_ROWS 200000
#define NIMG   500
#define DMETA  24
#define WIDTH  32
#define HID    64
#define DEPTH  20
#define MC     32

// ws layout (floats):
//   [0, 16000)        sums -> pooled (in-place normalize)
//   [16000, 56960)    w1t: transposed mlp_w1, w1t[l][j][k] = w1[l][k][j]
#define WS_SUMS  0
#define WS_W1T   16000

__device__ __forceinline__ uint32_t rotl32(uint32_t x, int r) {
    return (x << r) | (x >> (32 - r));
}

// JAX *partitionable* threefry bits for key (0,42), bit_width=32:
//   bits = bits1 ^ bits2 where (bits1,bits2) = threefry2x32((0,42), (j_hi, j_lo))
// For our sizes j_hi = 0. [jax_threefry_partitionable=True, JAX >= 0.4.36]
__device__ __forceinline__ uint32_t tf_bits(uint32_t j) {
    const uint32_t ks1 = 42u, ks2 = 0x1BD11BDAu ^ 42u;  // ks0 = 0
    uint32_t x0 = 0u;        // counts_hi (0) + ks0 (0)
    uint32_t x1 = j + ks1;   // counts_lo + ks1
#define R4(a,b,c,d) \
    x0 += x1; x1 = rotl32(x1,(a)); x1 ^= x0; \
    x0 += x1; x1 = rotl32(x1,(b)); x1 ^= x0; \
    x0 += x1; x1 = rotl32(x1,(c)); x1 ^= x0; \
    x0 += x1; x1 = rotl32(x1,(d)); x1 ^= x0;
    R4(13,15,26,6)  x0 += ks1; x1 += ks2 + 1u;
    R4(17,29,16,24) x0 += ks2; x1 += 0u + 2u;
    R4(13,15,26,6)  /* x0 += ks0 */ x1 += ks1 + 3u;
    R4(17,29,16,24) x0 += ks1; x1 += ks2 + 4u;
    R4(13,15,26,6)  x0 += ks2; x1 += 0u + 5u;
#undef R4
    return x0 ^ x1;
}

// JAX uniform(lo=nextafter(-1,0), hi=1) then sqrt(2)*erfinv.
__device__ __forceinline__ float bits_to_normal(uint32_t b) {
    float f = __uint_as_float((b >> 9) | 0x3f800000u) - 1.0f;  // [0,1)
    const float lo = -0.99999994f;                              // nextafter(-1,0)
    float u = f * 2.0f + lo;
    u = fmaxf(lo, u);
    return 1.41421356f * erfinvf(u);
}

// 20 residual MLP blocks, weights via wave-uniform (scalar) loads.
__device__ __forceinline__ void mlp20(float h[WIDTH],
                                      const float* __restrict__ w1t,
                                      const float* __restrict__ b1,
                                      const float* __restrict__ w2,
                                      const float* __restrict__ b2) {
#pragma unroll 1
    for (int l = 0; l < DEPTH; ++l) {
        const float* W1 = w1t + l * (WIDTH * HID);   // [j][k]
        const float* B1 = b1 + l * HID;
        const float* W2 = w2 + l * (HID * WIDTH);    // [j][k]
        const float* B2 = b2 + l * WIDTH;
        float acc[WIDTH];
#pragma unroll
        for (int k = 0; k < WIDTH; ++k) acc[k] = B2[k];
#pragma unroll 4
        for (int j = 0; j < HID; ++j) {
            float a = B1[j];
#pragma unroll
            for (int k = 0; k < WIDTH; ++k) a = fmaf(h[k], W1[j * 32 + k], a);
            a = fmaxf(a, 0.0f);
#pragma unroll
            for (int k = 0; k < WIDTH; ++k) acc[k] = fmaf(a, W2[j * 32 + k], acc[k]);
        }
#pragma unroll
        for (int k = 0; k < WIDTH; ++k) h[k] += acc[k];
    }
}

// prep: zero pooled sums; transpose w1 into ws
__global__ __launch_bounds__(256) void prep_kernel(const float* __restrict__ w1,
                                                   float* __restrict__ ws) {
    int t = blockIdx.x * 256 + threadIdx.x;
    if (t < NIMG * WIDTH) ws[WS_SUMS + t] = 0.0f;
    if (t < DEPTH * WIDTH * HID) {
        int l = t >> 11;          // /2048
        int r = t & 2047;
        int k = r >> 6;           // /64
        int j = r & 63;
        ws[WS_W1T + l * 2048 + j * 32 + k] = w1[t];
    }
}

// pass A: h0 = [metadata, iobs, sigiobs] @ w_img + b; MLP; plain atomic segment-sum
// block=64: exact grid (200000/64=3125), ~8% CU imbalance vs 25% at block=256.
// __launch_bounds__(64,3): VGPR cap ~170 so h[32]+acc[32] stay in arch VGPRs
// (round-4 counters: VGPR_Count=40 -> AGPR shuttling; occupancy was grid-limited
// at ~12 waves/CU anyway, so the compiler's high-occupancy choice bought nothing).
__global__ __launch_bounds__(64, 3) void pass_a(
    const float* __restrict__ md, const float* __restrict__ iobs,
    const float* __restrict__ sig, const float* __restrict__ wimg,
    const float* __restrict__ bimg, const float* __restrict__ w1t,
    const float* __restrict__ b1, const float* __restrict__ w2,
    const float* __restrict__ b2, const int* __restrict__ ids,
    float* __restrict__ sums) {
    int i = blockIdx.x * 64 + threadIdx.x;
    if (i >= N_ROWS) return;

    float x[26];
    const float4* m4 = reinterpret_cast<const float4*>(md + (size_t)i * DMETA);
#pragma unroll
    for (int q = 0; q < 6; ++q) {
        float4 v = m4[q];
        x[q * 4 + 0] = v.x; x[q * 4 + 1] = v.y; x[q * 4 + 2] = v.z; x[q * 4 + 3] = v.w;
    }
    x[24] = iobs[i];
    x[25] = sig[i];

    float h[WIDTH];
#pragma unroll
    for (int c = 0; c < WIDTH; ++c) h[c] = bimg[c];
#pragma unroll 2
    for (int d = 0; d < 26; ++d) {
#pragma unroll
        for (int c = 0; c < WIDTH; ++c) h[c] = fmaf(x[d], wimg[d * 32 + c], h[c]);
    }

    mlp20(h, w1t, b1, w2, b2);

    // literal per-row atomic segment-sum; channel order staggered by lane so a
    // wave's 64 lanes (mostly same image) hit 32 distinct addresses per step.
    int id = ids[i];
    int lane = threadIdx.x & 63;
#pragma unroll 1
    for (int cc = 0; cc < WIDTH; ++cc) {
        int c = (cc + lane) & 31;
        atomicAdd(&sums[id * 32 + c], h[c]);
    }
}

// normalize: pooled = sums / max(count,1), in-place
__global__ __launch_bounds__(256) void normalize_kernel(float* __restrict__ sums,
                                                        const int* __restrict__ cnts) {
    int t = blockIdx.x * 256 + threadIdx.x;
    if (t < NIMG * WIDTH) {
        int img = t >> 5;
        float c = (float)max(cnts[img], 1);
        sums[t] = sums[t] / c;
    }
}

// pass B: s0 = metadata @ w_scale + b + pooled[id]; MLP; head; sample; outputs
__global__ __launch_bounds__(64, 3) void pass_b(
    const float* __restrict__ md, const float* __restrict__ wsc,
    const float* __restrict__ bsc, const float* __restrict__ w1t,
    const float* __restrict__ b1, const float* __restrict__ w2,
    const float* __restrict__ b2, const float* __restrict__ wout,
    const float* __restrict__ bout, const int* __restrict__ ids,
    const float* __restrict__ pooled, float* __restrict__ out) {
    int i = blockIdx.x * 64 + threadIdx.x;
    if (i >= N_ROWS) return;

    float x[24];
    const float4* m4 = reinterpret_cast<const float4*>(md + (size_t)i * DMETA);
#pragma unroll
    for (int q = 0; q < 6; ++q) {
        float4 v = m4[q];
        x[q * 4 + 0] = v.x; x[q * 4 + 1] = v.y; x[q * 4 + 2] = v.z; x[q * 4 + 3] = v.w;
    }
    int id = ids[i];

    float h[WIDTH];
#pragma unroll
    for (int c = 0; c < WIDTH; ++c) h[c] = bsc[c] + pooled[id * 32 + c];
#pragma unroll 2
    for (int d = 0; d < DMETA; ++d) {
#pragma unroll
        for (int c = 0; c < WIDTH; ++c) h[c] = fmaf(x[d], wsc[d * 32 + c], h[c]);
    }

    mlp20(h, w1t, b1, w2, b2);

    float p0 = bout[0], p1 = bout[1];
#pragma unroll
    for (int c = 0; c < WIDTH; ++c) {
        p0 = fmaf(h[c], wout[c * 2 + 0], p0);
        p1 = fmaf(h[c], wout[c * 2 + 1], p1);
    }
    float loc = p0;
    // softplus = logaddexp(x,0) = max(x,0) + log1p(exp(-|x|))
    float scale = fmaxf(p1, 0.0f) + log1pf(expf(-fabsf(p1))) + 1e-12f;
    float ls = logf(scale);

    float klsum = 0.0f;  // sum over samples of (-0.5*n^2 + |z|)
    float* zrow = out + (size_t)i * MC;
#pragma unroll 4
    for (int t = 0; t < 16; ++t) {
        uint32_t j0 = (uint32_t)(t * N_ROWS) + (uint32_t)i;   // flat idx, sample t
        uint32_t j1 = j0 + 3200000u;                          // sample t+16
        float n0 = bits_to_normal(tf_bits(j0));
        float n1 = bits_to_normal(tf_bits(j1));
        float z0 = fmaf(scale, n0, loc);
        float z1 = fmaf(scale, n1, loc);
        zrow[t] = z0;
        zrow[t + 16] = z1;
        klsum += fmaf(-0.5f, n0 * n0, fabsf(z0));
        klsum += fmaf(-0.5f, n1 * n1, fabsf(z1));
    }
    // kl = KLW * ( mean(-0.5 n^2 + |z|) - log(scale) - 0.5*log(2pi) + log(2) )
    float kl = 0.01f * (klsum * (1.0f / 32.0f) - ls - 0.91893853320467274f + 0.69314718055994531f);
    out[(size_t)N_ROWS * MC + i] = kl;
}

extern "C" void kernel_launch(void* const* d_in, const int* in_sizes, int n_in,
                              void* d_out, int out_size, void* d_ws, size_t ws_size,
                              hipStream_t stream) {
    const float* md   = (const float*)d_in[0];
    const float* iobs = (const float*)d_in[1];
    const float* sig  = (const float*)d_in[2];
    const float* wimg = (const float*)d_in[3];
    const float* bimg = (const float*)d_in[4];
    const float* wsc  = (const float*)d_in[5];
    const float* bsc  = (const float*)d_in[6];
    const float* w1   = (const float*)d_in[7];
    const float* b1   = (const float*)d_in[8];
    const float* w2   = (const float*)d_in[9];
    const float* b2   = (const float*)d_in[10];
    const float* wout = (const float*)d_in[11];
    const float* bout = (const float*)d_in[12];
    const int* ids    = (const int*)d_in[13];
    const int* cnts   = (const int*)d_in[14];
    float* out = (float*)d_out;
    float* ws  = (float*)d_ws;
    float* sums = ws + WS_SUMS;
    float* w1t  = ws + WS_W1T;

    const int nblk = (N_ROWS + 63) / 64;   // 3125, exact
    prep_kernel<<<(DEPTH * WIDTH * HID + 255) / 256, 256, 0, stream>>>(w1, ws);
    pass_a<<<nblk, 64, 0, stream>>>(md, iobs, sig, wimg, bimg, w1t, b1, w2, b2, ids, sums);
    normalize_kernel<<<(NIMG * WIDTH + 255) / 256, 256, 0, stream>>>(sums, cnts);
    pass_b<<<nblk, 64, 0, stream>>>(md, wsc, bsc, w1t, b1, w2, b2, wout, bout, ids, sums, out);
}

// Round 6
// 568.932 us; speedup vs baseline: 2.4046x; 2.4046x over previous
//
#include <hip/hip_runtime.h>
#include <stdint.h>

#define N_ROWS 200000
#define NIMG   500
#define DMETA  24
#define WIDTH  32
#define HID    64
#define DEPTH  20
#define MC     32

typedef __attribute__((ext_vector_type(8))) short bf16x8;
typedef __attribute__((ext_vector_type(4))) float f32x4;

// ws layout (bytes):
//   0        .. 64000    : sums/pooled (16000 f32)
//   64000    .. 145920   : w1 frags hi (20*4*512 bf16)
//   145920   .. 227840   : w1 frags lo
//   227840   .. 309760   : w2 frags hi (20*2*2*512)
//   309760   .. 391680   : w2 frags lo
//   391680   .. 393728   : wimg frags hi (2*512)
//   393728   .. 395776   : wimg frags lo
//   395776   .. 397824   : wsc frags hi
//   397824   .. 399872   : wsc frags lo
#define OFF_W1H  64000
#define OFF_W1L  145920
#define OFF_W2H  227840
#define OFF_W2L  309760
#define OFF_WIH  391680
#define OFF_WIL  393728
#define OFF_WSH  395776
#define OFF_WSL  397824

__device__ __forceinline__ uint32_t rotl32(uint32_t x, int r) {
    return (x << r) | (x >> (32 - r));
}

// JAX partitionable threefry, key (0,42): bits(j) = x0^x1 of threefry2x32((0,42),(0,j))
__device__ __forceinline__ uint32_t tf_bits(uint32_t j) {
    const uint32_t ks1 = 42u, ks2 = 0x1BD11BDAu ^ 42u;
    uint32_t x0 = 0u, x1 = j + ks1;
#define R4(a,b,c,d) \
    x0 += x1; x1 = rotl32(x1,(a)); x1 ^= x0; \
    x0 += x1; x1 = rotl32(x1,(b)); x1 ^= x0; \
    x0 += x1; x1 = rotl32(x1,(c)); x1 ^= x0; \
    x0 += x1; x1 = rotl32(x1,(d)); x1 ^= x0;
    R4(13,15,26,6)  x0 += ks1; x1 += ks2 + 1u;
    R4(17,29,16,24) x0 += ks2; x1 += 0u + 2u;
    R4(13,15,26,6)                x1 += ks1 + 3u;
    R4(17,29,16,24) x0 += ks1; x1 += ks2 + 4u;
    R4(13,15,26,6)  x0 += ks2; x1 += 0u + 5u;
#undef R4
    return x0 ^ x1;
}

__device__ __forceinline__ float bits_to_normal(uint32_t b) {
    float f = __uint_as_float((b >> 9) | 0x3f800000u) - 1.0f;
    const float lo = -0.99999994f;
    float u = fmaxf(lo, f * 2.0f + lo);
    return 1.41421356f * erfinvf(u);
}

// bf16 round-to-nearest-even split: x ~= hi + lo (each bf16), rel err ~2^-16
__device__ __forceinline__ void split1(float x, short& hi, short& lo) {
    uint32_t b = __float_as_uint(x);
    uint32_t hb = (b + 0x7FFFu + ((b >> 16) & 1u)) & 0xFFFF0000u;
    hi = (short)(hb >> 16);
    float r = x - __uint_as_float(hb);
    uint32_t b2 = __float_as_uint(r);
    lo = (short)((b2 + 0x7FFFu + ((b2 >> 16) & 1u)) >> 16);
}

__device__ __forceinline__ void split8(const float* x, bf16x8& hi, bf16x8& lo) {
#pragma unroll
    for (int j = 0; j < 8; ++j) {
        short h, l;
        split1(x[j], h, l);
        hi[j] = h; lo[j] = l;
    }
}

__device__ __forceinline__ bf16x8 ldfrag(const short* p) {
    return *(const bf16x8*)p;
}

// 20 residual blocks via 16x16x32 bf16 MFMA, split-precision (hi/lo).
// Wave owns 16 rows. hC = master state in C-layout: hC[t*4+r] = h[m=q*4+r][n=16t+c].
// A-layout: A[m=lane&15][k=(lane>>4)*8+j]; B: B[k=(lane>>4)*8+j][n=lane&15].
__device__ __forceinline__ void mlp20_mfma(
    float hC[8], const short* __restrict__ w1fh, const short* __restrict__ w1fl,
    const short* __restrict__ w2fh, const short* __restrict__ w2fl,
    const float* __restrict__ b1, const float* __restrict__ b2,
    float* smw, int lane, int q, int c) {
#pragma unroll 1
    for (int l = 0; l < DEPTH; ++l) {
        // --- round trip 1: hC (C-layout) -> LDS -> A-frag of h[16,32]
#pragma unroll
        for (int t = 0; t < 2; ++t)
#pragma unroll
            for (int r = 0; r < 4; ++r)
                smw[(q * 4 + r) * 68 + 16 * t + c] = hC[t * 4 + r];
        float a1[8];
        {
            const f32x4* rp = (const f32x4*)(smw + c * 68 + q * 8);
            f32x4 v0 = rp[0], v1 = rp[1];
#pragma unroll
            for (int j = 0; j < 4; ++j) { a1[j] = v0[j]; a1[4 + j] = v1[j]; }
        }
        bf16x8 ah, al;
        split8(a1, ah, al);
        // --- stage 1: H1 = relu(h @ W1 + b1), 4 n-tiles
        float C1v[16];
#pragma unroll
        for (int t = 0; t < 4; ++t) {
            bf16x8 bh = ldfrag(w1fh + (((l * 4 + t) << 9) + (lane << 3)));
            bf16x8 bl = ldfrag(w1fl + (((l * 4 + t) << 9) + (lane << 3)));
            f32x4 acc = {0.f, 0.f, 0.f, 0.f};
            acc = __builtin_amdgcn_mfma_f32_16x16x32_bf16(ah, bh, acc, 0, 0, 0);
            acc = __builtin_amdgcn_mfma_f32_16x16x32_bf16(ah, bl, acc, 0, 0, 0);
            acc = __builtin_amdgcn_mfma_f32_16x16x32_bf16(al, bh, acc, 0, 0, 0);
            float bb = b1[l * 64 + 16 * t + c];
#pragma unroll
            for (int r = 0; r < 4; ++r) C1v[t * 4 + r] = fmaxf(acc[r] + bb, 0.0f);
        }
        // --- round trip 2: H1 (C-layout) -> LDS -> A-frags of H1[16,64]
#pragma unroll
        for (int t = 0; t < 4; ++t)
#pragma unroll
            for (int r = 0; r < 4; ++r)
                smw[(q * 4 + r) * 68 + 16 * t + c] = C1v[t * 4 + r];
        bf16x8 a2h[2], a2l[2];
#pragma unroll
        for (int kf = 0; kf < 2; ++kf) {
            float a2[8];
            const f32x4* rp = (const f32x4*)(smw + c * 68 + kf * 32 + q * 8);
            f32x4 v0 = rp[0], v1 = rp[1];
#pragma unroll
            for (int j = 0; j < 4; ++j) { a2[j] = v0[j]; a2[4 + j] = v1[j]; }
            split8(a2, a2h[kf], a2l[kf]);
        }
        // --- stage 2: h += relu(H1) @ W2 + b2 (accumulate into residual C-regs)
#pragma unroll
        for (int t2 = 0; t2 < 2; ++t2) {
            f32x4 acc;
#pragma unroll
            for (int r = 0; r < 4; ++r) acc[r] = hC[t2 * 4 + r];
#pragma unroll
            for (int kf = 0; kf < 2; ++kf) {
                int fi = ((((l * 2 + kf) * 2 + t2) << 9) + (lane << 3));
                bf16x8 bh = ldfrag(w2fh + fi);
                bf16x8 bl = ldfrag(w2fl + fi);
                acc = __builtin_amdgcn_mfma_f32_16x16x32_bf16(a2h[kf], bh, acc, 0, 0, 0);
                acc = __builtin_amdgcn_mfma_f32_16x16x32_bf16(a2h[kf], bl, acc, 0, 0, 0);
                acc = __builtin_amdgcn_mfma_f32_16x16x32_bf16(a2l[kf], bh, acc, 0, 0, 0);
            }
            float bb = b2[l * 32 + 16 * t2 + c];
#pragma unroll
            for (int r = 0; r < 4; ++r) hC[t2 * 4 + r] = acc[r] + bb;
        }
    }
}

// prep: zero sums; pre-split all weights into fragment-ordered bf16 hi/lo tables.
__global__ __launch_bounds__(256) void prep_kernel(
    const float* __restrict__ w1, const float* __restrict__ w2,
    const float* __restrict__ wimg, const float* __restrict__ wsc,
    char* __restrict__ wsb) {
    int t = blockIdx.x * 256 + threadIdx.x;
    float* sums = (float*)wsb;
    if (t < 16000) { sums[t] = 0.0f; return; }
    t -= 16000;
    if (t < 40960) {  // w1 frags: [l][t][lane][j]
        int l = t >> 11, r = t & 2047, tt = r >> 9, r2 = r & 511;
        int lane = r2 >> 3, j = r2 & 7;
        int k = (lane >> 4) * 8 + j, n = 16 * tt + (lane & 15);
        short h, lo;
        split1(w1[l * 2048 + k * 64 + n], h, lo);
        ((short*)(wsb + OFF_W1H))[t] = h;
        ((short*)(wsb + OFF_W1L))[t] = lo;
        return;
    }
    t -= 40960;
    if (t < 40960) {  // w2 frags: [l][kf][t2][lane][j]
        int l = t >> 11, r = t & 2047, kf = r >> 10, r2 = r & 1023;
        int t2 = r2 >> 9, r3 = r2 & 511, lane = r3 >> 3, j = r3 & 7;
        int k = kf * 32 + (lane >> 4) * 8 + j, n = 16 * t2 + (lane & 15);
        short h, lo;
        split1(w2[l * 2048 + k * 32 + n], h, lo);
        ((short*)(wsb + OFF_W2H))[t] = h;
        ((short*)(wsb + OFF_W2L))[t] = lo;
        return;
    }
    t -= 40960;
    if (t < 1024) {  // wimg frags (K padded 26->32)
        int tt = t >> 9, r = t & 511, lane = r >> 3, j = r & 7;
        int k = (lane >> 4) * 8 + j, n = 16 * tt + (lane & 15);
        float v = (k < 26) ? wimg[k * 32 + n] : 0.0f;
        short h, lo;
        split1(v, h, lo);
        ((short*)(wsb + OFF_WIH))[t] = h;
        ((short*)(wsb + OFF_WIL))[t] = lo;
        return;
    }
    t -= 1024;
    if (t < 1024) {  // wscale frags (K padded 24->32)
        int tt = t >> 9, r = t & 511, lane = r >> 3, j = r & 7;
        int k = (lane >> 4) * 8 + j, n = 16 * tt + (lane & 15);
        float v = (k < 24) ? wsc[k * 32 + n] : 0.0f;
        short h, lo;
        split1(v, h, lo);
        ((short*)(wsb + OFF_WSH))[t] = h;
        ((short*)(wsb + OFF_WSL))[t] = lo;
        return;
    }
}

// pass A: input proj (MFMA) -> mlp20 -> atomic segment-sum. Wave = 16 rows.
__global__ __launch_bounds__(256) void pass_a(
    const float* __restrict__ md, const float* __restrict__ iobs,
    const float* __restrict__ sig, const float* __restrict__ bimg,
    const char* __restrict__ wsb, const float* __restrict__ b1,
    const float* __restrict__ b2, const int* __restrict__ ids,
    float* __restrict__ sums) {
    __shared__ float smat[4][16 * 68];
    int lane = threadIdx.x & 63, w = threadIdx.x >> 6;
    int q = lane >> 4, c = lane & 15;
    int i0 = (blockIdx.x * 4 + w) * 16;
    float* smw = &smat[w][0];

    // A-frag of X[16,32] (cols 0..23 md, 24 iobs, 25 sig, 26..31 zero)
    float xa[8];
    if (q < 3) {
        const f32x4* rp = (const f32x4*)(md + (size_t)(i0 + c) * DMETA + q * 8);
        f32x4 v0 = rp[0], v1 = rp[1];
#pragma unroll
        for (int j = 0; j < 4; ++j) { xa[j] = v0[j]; xa[4 + j] = v1[j]; }
    } else {
        xa[0] = iobs[i0 + c]; xa[1] = sig[i0 + c];
#pragma unroll
        for (int j = 2; j < 8; ++j) xa[j] = 0.0f;
    }
    bf16x8 ah, al;
    split8(xa, ah, al);

    float hC[8];
#pragma unroll
    for (int t = 0; t < 2; ++t) {
        bf16x8 bh = ldfrag((const short*)(wsb + OFF_WIH) + ((t << 9) + (lane << 3)));
        bf16x8 bl = ldfrag((const short*)(wsb + OFF_WIL) + ((t << 9) + (lane << 3)));
        f32x4 acc = {0.f, 0.f, 0.f, 0.f};
        acc = __builtin_amdgcn_mfma_f32_16x16x32_bf16(ah, bh, acc, 0, 0, 0);
        acc = __builtin_amdgcn_mfma_f32_16x16x32_bf16(ah, bl, acc, 0, 0, 0);
        acc = __builtin_amdgcn_mfma_f32_16x16x32_bf16(al, bh, acc, 0, 0, 0);
        float bb = bimg[16 * t + c];
#pragma unroll
        for (int r = 0; r < 4; ++r) hC[t * 4 + r] = acc[r] + bb;
    }

    mlp20_mfma(hC, (const short*)(wsb + OFF_W1H), (const short*)(wsb + OFF_W1L),
               (const short*)(wsb + OFF_W2H), (const short*)(wsb + OFF_W2L),
               b1, b2, smw, lane, q, c);

    int idv[4];
#pragma unroll
    for (int r = 0; r < 4; ++r) idv[r] = ids[i0 + q * 4 + r];
#pragma unroll
    for (int t = 0; t < 2; ++t)
#pragma unroll
        for (int r = 0; r < 4; ++r)
            atomicAdd(&sums[idv[r] * 32 + 16 * t + c], hC[t * 4 + r]);
}

__global__ __launch_bounds__(256) void normalize_kernel(float* __restrict__ sums,
                                                        const int* __restrict__ cnts) {
    int t = blockIdx.x * 256 + threadIdx.x;
    if (t < NIMG * WIDTH) {
        int img = t >> 5;
        float cc = (float)max(cnts[img], 1);
        sums[t] = sums[t] / cc;
    }
}

// pass B: input proj + pooled -> mlp20 -> head -> sample -> z, kl. Wave = 16 rows.
__global__ __launch_bounds__(256) void pass_b(
    const float* __restrict__ md, const float* __restrict__ bsc,
    const char* __restrict__ wsb, const float* __restrict__ b1,
    const float* __restrict__ b2, const float* __restrict__ wout,
    const float* __restrict__ bout, const int* __restrict__ ids,
    const float* __restrict__ pooled, float* __restrict__ out) {
    __shared__ float smat[4][16 * 68];
    __shared__ float sls[4][32];
    int lane = threadIdx.x & 63, w = threadIdx.x >> 6;
    int q = lane >> 4, c = lane & 15;
    int i0 = (blockIdx.x * 4 + w) * 16;
    float* smw = &smat[w][0];

    float xa[8];
    if (q < 3) {
        const f32x4* rp = (const f32x4*)(md + (size_t)(i0 + c) * DMETA + q * 8);
        f32x4 v0 = rp[0], v1 = rp[1];
#pragma unroll
        for (int j = 0; j < 4; ++j) { xa[j] = v0[j]; xa[4 + j] = v1[j]; }
    } else {
#pragma unroll
        for (int j = 0; j < 8; ++j) xa[j] = 0.0f;
    }
    bf16x8 ah, al;
    split8(xa, ah, al);

    int idv[4];
#pragma unroll
    for (int r = 0; r < 4; ++r) idv[r] = ids[i0 + q * 4 + r];

    float hC[8];
#pragma unroll
    for (int t = 0; t < 2; ++t) {
        bf16x8 bh = ldfrag((const short*)(wsb + OFF_WSH) + ((t << 9) + (lane << 3)));
        bf16x8 bl = ldfrag((const short*)(wsb + OFF_WSL) + ((t << 9) + (lane << 3)));
        f32x4 acc = {0.f, 0.f, 0.f, 0.f};
        acc = __builtin_amdgcn_mfma_f32_16x16x32_bf16(ah, bh, acc, 0, 0, 0);
        acc = __builtin_amdgcn_mfma_f32_16x16x32_bf16(ah, bl, acc, 0, 0, 0);
        acc = __builtin_amdgcn_mfma_f32_16x16x32_bf16(al, bh, acc, 0, 0, 0);
        float bb = bsc[16 * t + c];
#pragma unroll
        for (int r = 0; r < 4; ++r)
            hC[t * 4 + r] = acc[r] + bb + pooled[idv[r] * 32 + 16 * t + c];
    }

    mlp20_mfma(hC, (const short*)(wsb + OFF_W1H), (const short*)(wsb + OFF_W1L),
               (const short*)(wsb + OFF_W2H), (const short*)(wsb + OFF_W2L),
               b1, b2, smw, lane, q, c);

    // head: params[m] = h[m]@wout + bout; rows m=q*4+r live across the 16 c-lanes
    float wo0[2], wo1[2];
#pragma unroll
    for (int t = 0; t < 2; ++t) {
        float2 wv = ((const float2*)wout)[16 * t + c];
        wo0[t] = wv.x; wo1[t] = wv.y;
    }
    float p0r[4], p1r[4];
#pragma unroll
    for (int r = 0; r < 4; ++r) {
        p0r[r] = hC[r] * wo0[0] + hC[4 + r] * wo0[1];
        p1r[r] = hC[r] * wo1[0] + hC[4 + r] * wo1[1];
    }
#pragma unroll
    for (int m = 1; m < 16; m <<= 1) {
#pragma unroll
        for (int r = 0; r < 4; ++r) {
            p0r[r] += __shfl_xor(p0r[r], m, 64);
            p1r[r] += __shfl_xor(p1r[r], m, 64);
        }
    }
    if (c == 0) {
#pragma unroll
        for (int r = 0; r < 4; ++r) {
            float loc = p0r[r] + bout[0];
            float pb = p1r[r] + bout[1];
            float scale = fmaxf(pb, 0.0f) + log1pf(expf(-fabsf(pb))) + 1e-12f;
            sls[w][q * 4 + r] = loc;
            sls[w][16 + q * 4 + r] = scale;
        }
    }
    // sampling: lane handles row (i0+c), draws t = q*8 + jj
    float L = sls[w][c];
    float S = sls[w][16 + c];
    float lsg = logf(S);
    int row = i0 + c;
    float kp = 0.0f;
    f32x4 zlo, zhi;
#pragma unroll
    for (int jj = 0; jj < 8; ++jj) {
        uint32_t j = (uint32_t)((q * 8 + jj) * N_ROWS) + (uint32_t)row;
        float n = bits_to_normal(tf_bits(j));
        float z = fmaf(S, n, L);
        if (jj < 4) zlo[jj] = z; else zhi[jj - 4] = z;
        kp += fmaf(-0.5f, n * n, fabsf(z));
    }
    *(f32x4*)(out + (size_t)row * MC + q * 8) = zlo;
    *(f32x4*)(out + (size_t)row * MC + q * 8 + 4) = zhi;
    kp += __shfl_xor(kp, 16, 64);
    kp += __shfl_xor(kp, 32, 64);
    if (q == 0) {
        out[(size_t)N_ROWS * MC + row] =
            0.01f * (kp * (1.0f / 32.0f) - lsg - 0.91893853320467274f + 0.69314718055994531f);
    }
}

extern "C" void kernel_launch(void* const* d_in, const int* in_sizes, int n_in,
                              void* d_out, int out_size, void* d_ws, size_t ws_size,
                              hipStream_t stream) {
    const float* md   = (const float*)d_in[0];
    const float* iobs = (const float*)d_in[1];
    const float* sig  = (const float*)d_in[2];
    const float* wimg = (const float*)d_in[3];
    const float* bimg = (const float*)d_in[4];
    const float* wsc  = (const float*)d_in[5];
    const float* bsc  = (const float*)d_in[6];
    const float* w1   = (const float*)d_in[7];
    const float* b1   = (const float*)d_in[8];
    const float* w2   = (const float*)d_in[9];
    const float* b2   = (const float*)d_in[10];
    const float* wout = (const float*)d_in[11];
    const float* bout = (const float*)d_in[12];
    const int* ids    = (const int*)d_in[13];
    const int* cnts   = (const int*)d_in[14];
    float* out = (float*)d_out;
    char* wsb = (char*)d_ws;
    float* sums = (float*)wsb;

    const int nblk = N_ROWS / 64;  // 3125 blocks x 4 waves x 16 rows
    prep_kernel<<<391, 256, 0, stream>>>(w1, w2, wimg, wsc, wsb);
    pass_a<<<nblk, 256, 0, stream>>>(md, iobs, sig, bimg, wsb, b1, b2, ids, sums);
    normalize_kernel<<<(NIMG * WIDTH + 255) / 256, 256, 0, stream>>>(sums, cnts);
    pass_b<<<nblk, 256, 0, stream>>>(md, bsc, wsb, b1, b2, wout, bout, ids, sums, out);
}

// Round 7
// 395.421 us; speedup vs baseline: 3.4597x; 1.4388x over previous
//
#include <hip/hip_runtime.h>
#include <stdint.h>

#define N_ROWS 200000
#define NIMG   500
#define DMETA  24
#define WIDTH  32
#define HID    64
#define DEPTH  20
#define MC     32
#define NSTR   18   // n-major LDS stride (dwords): even (b64 align), 8*NSTR%32=16 -> 2-way (free)

typedef __attribute__((ext_vector_type(8))) short bf16x8;
typedef __attribute__((ext_vector_type(4))) float f32x4;

#define MFMA(a, b, acc) __builtin_amdgcn_mfma_f32_16x16x32_bf16((a), (b), (acc), 0, 0, 0)

// ws layout (bytes): same as round 6
#define OFF_W1H  64000
#define OFF_W1L  145920
#define OFF_W2H  227840
#define OFF_W2L  309760
#define OFF_WIH  391680
#define OFF_WIL  393728
#define OFF_WSH  395776
#define OFF_WSL  397824

__device__ __forceinline__ uint32_t rotl32(uint32_t x, int r) {
    return (x << r) | (x >> (32 - r));
}

// JAX partitionable threefry, key (0,42): bits(j) = x0^x1 of threefry2x32((0,42),(0,j))
__device__ __forceinline__ uint32_t tf_bits(uint32_t j) {
    const uint32_t ks1 = 42u, ks2 = 0x1BD11BDAu ^ 42u;
    uint32_t x0 = 0u, x1 = j + ks1;
#define R4(a,b,c,d) \
    x0 += x1; x1 = rotl32(x1,(a)); x1 ^= x0; \
    x0 += x1; x1 = rotl32(x1,(b)); x1 ^= x0; \
    x0 += x1; x1 = rotl32(x1,(c)); x1 ^= x0; \
    x0 += x1; x1 = rotl32(x1,(d)); x1 ^= x0;
    R4(13,15,26,6)  x0 += ks1; x1 += ks2 + 1u;
    R4(17,29,16,24) x0 += ks2; x1 += 0u + 2u;
    R4(13,15,26,6)                x1 += ks1 + 3u;
    R4(17,29,16,24) x0 += ks1; x1 += ks2 + 4u;
    R4(13,15,26,6)  x0 += ks2; x1 += 0u + 5u;
#undef R4
    return x0 ^ x1;
}

__device__ __forceinline__ float bits_to_normal(uint32_t b) {
    float f = __uint_as_float((b >> 9) | 0x3f800000u) - 1.0f;
    const float lo = -0.99999994f;
    float u = fmaxf(lo, f * 2.0f + lo);
    return 1.41421356f * erfinvf(u);
}

// split (prep, scalar): round-half-up hi, truncated lo. |x - hi - lo| <~ 2^-16 |x|
__device__ __forceinline__ void split1(float x, short& hi, short& lo) {
    uint32_t b = __float_as_uint(x);
    uint32_t a = b + 0x8000u;
    hi = (short)(a >> 16);
    float r = x - __uint_as_float(a & 0xFFFF0000u);
    lo = (short)(__float_as_uint(r) >> 16);
}

// vector split+pack: 8 f32 -> bf16x8 hi, bf16x8 lo via v_perm packing (~4 VALU/elem)
__device__ __forceinline__ void split8p(const float* x, bf16x8& hi, bf16x8& lo) {
    uint32_t hu[4], lu[4];
#pragma unroll
    for (int p = 0; p < 4; ++p) {
        uint32_t b0 = __float_as_uint(x[2 * p]);
        uint32_t b1 = __float_as_uint(x[2 * p + 1]);
        uint32_t a0 = b0 + 0x8000u, a1 = b1 + 0x8000u;
        hu[p] = __builtin_amdgcn_perm(a1, a0, 0x07060302u);  // hi16(a1):hi16(a0)
        float r0 = x[2 * p] - __uint_as_float(a0 & 0xFFFF0000u);
        float r1 = x[2 * p + 1] - __uint_as_float(a1 & 0xFFFF0000u);
        lu[p] = __builtin_amdgcn_perm(__float_as_uint(r1), __float_as_uint(r0), 0x07060302u);
    }
    __builtin_memcpy(&hi, hu, 16);
    __builtin_memcpy(&lo, lu, 16);
}

// 20 residual blocks, two independent 16-row tiles per wave (ILP for latency hiding).
// LDS n-major: element (m,n) at smw[n*NSTR + m]; C-layout rows r-contiguous -> b64 writes.
__device__ __forceinline__ void mlp20_x2(
    float* hC0, float* hC1, float* smw0, float* smw1,
    const short* __restrict__ w1fh, const short* __restrict__ w1fl,
    const short* __restrict__ w2fh, const short* __restrict__ w2fl,
    const float* __restrict__ b1, const float* __restrict__ b2,
    int lane, int q, int c) {
    float2* sm20 = (float2*)smw0;
    float2* sm21 = (float2*)smw1;
#pragma unroll 1
    for (int l = 0; l < DEPTH; ++l) {
        // RT1: hC (C-layout) -> LDS, b64
#pragma unroll
        for (int t = 0; t < 2; ++t) {
            int bi = (16 * t + c) * 9 + 2 * q;
            sm20[bi]     = make_float2(hC0[t * 4 + 0], hC0[t * 4 + 1]);
            sm20[bi + 1] = make_float2(hC0[t * 4 + 2], hC0[t * 4 + 3]);
            sm21[bi]     = make_float2(hC1[t * 4 + 0], hC1[t * 4 + 1]);
            sm21[bi + 1] = make_float2(hC1[t * 4 + 2], hC1[t * 4 + 3]);
        }
        float a0[8], a1[8];
#pragma unroll
        for (int j = 0; j < 8; ++j) a0[j] = smw0[(q * 8 + j) * NSTR + c];
#pragma unroll
        for (int j = 0; j < 8; ++j) a1[j] = smw1[(q * 8 + j) * NSTR + c];
        bf16x8 ah0, al0, ah1, al1;
        split8p(a0, ah0, al0);
        split8p(a1, ah1, al1);
        // stage 1: H1 = relu(h @ W1 + b1); weight frags shared by both tiles
        float C1v0[16], C1v1[16];
#pragma unroll
        for (int t = 0; t < 4; ++t) {
            const int fi = (((l * 4 + t) << 9) + (lane << 3));
            bf16x8 bh = *(const bf16x8*)(w1fh + fi);
            bf16x8 bl = *(const bf16x8*)(w1fl + fi);
            float bb = b1[l * 64 + 16 * t + c];
            f32x4 acc = {0.f, 0.f, 0.f, 0.f};
            acc = MFMA(ah0, bh, acc); acc = MFMA(ah0, bl, acc); acc = MFMA(al0, bh, acc);
            f32x4 acd = {0.f, 0.f, 0.f, 0.f};
            acd = MFMA(ah1, bh, acd); acd = MFMA(ah1, bl, acd); acd = MFMA(al1, bh, acd);
#pragma unroll
            for (int r = 0; r < 4; ++r) {
                C1v0[t * 4 + r] = fmaxf(acc[r] + bb, 0.0f);
                C1v1[t * 4 + r] = fmaxf(acd[r] + bb, 0.0f);
            }
        }
        // RT2: H1 -> LDS, b64
#pragma unroll
        for (int t = 0; t < 4; ++t) {
            int bi = (16 * t + c) * 9 + 2 * q;
            sm20[bi]     = make_float2(C1v0[t * 4 + 0], C1v0[t * 4 + 1]);
            sm20[bi + 1] = make_float2(C1v0[t * 4 + 2], C1v0[t * 4 + 3]);
            sm21[bi]     = make_float2(C1v1[t * 4 + 0], C1v1[t * 4 + 1]);
            sm21[bi + 1] = make_float2(C1v1[t * 4 + 2], C1v1[t * 4 + 3]);
        }
        // stage 2: h += H1 @ W2 + b2 (accumulate into residual C-regs)
        f32x4 acc0[2], acc1[2];
#pragma unroll
        for (int t2 = 0; t2 < 2; ++t2)
#pragma unroll
            for (int r = 0; r < 4; ++r) {
                acc0[t2][r] = hC0[t2 * 4 + r];
                acc1[t2][r] = hC1[t2 * 4 + r];
            }
#pragma unroll
        for (int kf = 0; kf < 2; ++kf) {
            float e0[8], e1[8];
#pragma unroll
            for (int j = 0; j < 8; ++j) e0[j] = smw0[(kf * 32 + q * 8 + j) * NSTR + c];
#pragma unroll
            for (int j = 0; j < 8; ++j) e1[j] = smw1[(kf * 32 + q * 8 + j) * NSTR + c];
            bf16x8 xh0, xl0, xh1, xl1;
            split8p(e0, xh0, xl0);
            split8p(e1, xh1, xl1);
#pragma unroll
            for (int t2 = 0; t2 < 2; ++t2) {
                const int fi = ((((l * 2 + kf) * 2 + t2) << 9) + (lane << 3));
                bf16x8 bh = *(const bf16x8*)(w2fh + fi);
                bf16x8 bl = *(const bf16x8*)(w2fl + fi);
                acc0[t2] = MFMA(xh0, bh, acc0[t2]);
                acc0[t2] = MFMA(xh0, bl, acc0[t2]);
                acc0[t2] = MFMA(xl0, bh, acc0[t2]);
                acc1[t2] = MFMA(xh1, bh, acc1[t2]);
                acc1[t2] = MFMA(xh1, bl, acc1[t2]);
                acc1[t2] = MFMA(xl1, bh, acc1[t2]);
            }
        }
#pragma unroll
        for (int t2 = 0; t2 < 2; ++t2) {
            float bb = b2[l * 32 + 16 * t2 + c];
#pragma unroll
            for (int r = 0; r < 4; ++r) {
                hC0[t2 * 4 + r] = acc0[t2][r] + bb;
                hC1[t2 * 4 + r] = acc1[t2][r] + bb;
            }
        }
    }
}

// input projection for one 16-row tile -> hC (C-layout), using wimg/wsc frags
__device__ __forceinline__ void input_proj(
    const bf16x8& ah, const bf16x8& al, const short* __restrict__ wfh,
    const short* __restrict__ wfl, const float* __restrict__ bias,
    float* hC, int lane, int c) {
#pragma unroll
    for (int t = 0; t < 2; ++t) {
        bf16x8 bh = *(const bf16x8*)(wfh + ((t << 9) + (lane << 3)));
        bf16x8 bl = *(const bf16x8*)(wfl + ((t << 9) + (lane << 3)));
        f32x4 acc = {0.f, 0.f, 0.f, 0.f};
        acc = MFMA(ah, bh, acc); acc = MFMA(ah, bl, acc); acc = MFMA(al, bh, acc);
        float bb = bias[16 * t + c];
#pragma unroll
        for (int r = 0; r < 4; ++r) hC[t * 4 + r] = acc[r] + bb;
    }
}

// prep: zero sums; pre-split all weights into fragment-ordered bf16 hi/lo tables.
__global__ __launch_bounds__(256) void prep_kernel(
    const float* __restrict__ w1, const float* __restrict__ w2,
    const float* __restrict__ wimg, const float* __restrict__ wsc,
    char* __restrict__ wsb) {
    int t = blockIdx.x * 256 + threadIdx.x;
    float* sums = (float*)wsb;
    if (t < 16000) { sums[t] = 0.0f; return; }
    t -= 16000;
    if (t < 40960) {  // w1 frags: [l][t][lane][j]
        int l = t >> 11, r = t & 2047, tt = r >> 9, r2 = r & 511;
        int lane = r2 >> 3, j = r2 & 7;
        int k = (lane >> 4) * 8 + j, n = 16 * tt + (lane & 15);
        short h, lo;
        split1(w1[l * 2048 + k * 64 + n], h, lo);
        ((short*)(wsb + OFF_W1H))[t] = h;
        ((short*)(wsb + OFF_W1L))[t] = lo;
        return;
    }
    t -= 40960;
    if (t < 40960) {  // w2 frags: [l][kf][t2][lane][j]
        int l = t >> 11, r = t & 2047, kf = r >> 10, r2 = r & 1023;
        int t2 = r2 >> 9, r3 = r2 & 511, lane = r3 >> 3, j = r3 & 7;
        int k = kf * 32 + (lane >> 4) * 8 + j, n = 16 * t2 + (lane & 15);
        short h, lo;
        split1(w2[l * 2048 + k * 32 + n], h, lo);
        ((short*)(wsb + OFF_W2H))[t] = h;
        ((short*)(wsb + OFF_W2L))[t] = lo;
        return;
    }
    t -= 40960;
    if (t < 1024) {  // wimg frags (K padded 26->32)
        int tt = t >> 9, r = t & 511, lane = r >> 3, j = r & 7;
        int k = (lane >> 4) * 8 + j, n = 16 * tt + (lane & 15);
        float v = (k < 26) ? wimg[k * 32 + n] : 0.0f;
        short h, lo;
        split1(v, h, lo);
        ((short*)(wsb + OFF_WIH))[t] = h;
        ((short*)(wsb + OFF_WIL))[t] = lo;
        return;
    }
    t -= 1024;
    if (t < 1024) {  // wscale frags (K padded 24->32)
        int tt = t >> 9, r = t & 511, lane = r >> 3, j = r & 7;
        int k = (lane >> 4) * 8 + j, n = 16 * tt + (lane & 15);
        float v = (k < 24) ? wsc[k * 32 + n] : 0.0f;
        short h, lo;
        split1(v, h, lo);
        ((short*)(wsb + OFF_WSH))[t] = h;
        ((short*)(wsb + OFF_WSL))[t] = lo;
        return;
    }
}

// load A-frag of X[16,32] for rows base..base+15 (cols: 24 md, iobs, sig, pad)
__device__ __forceinline__ void load_xfrag(
    const float* __restrict__ md, const float* __restrict__ iobs,
    const float* __restrict__ sig, int base, int q, int c,
    bf16x8& ah, bf16x8& al) {
    float xa[8];
    if (q < 3) {
        const f32x4* rp = (const f32x4*)(md + (size_t)(base + c) * DMETA + q * 8);
        f32x4 v0 = rp[0], v1 = rp[1];
#pragma unroll
        for (int j = 0; j < 4; ++j) { xa[j] = v0[j]; xa[4 + j] = v1[j]; }
    } else {
        xa[0] = iobs ? iobs[base + c] : 0.0f;
        xa[1] = sig ? sig[base + c] : 0.0f;
#pragma unroll
        for (int j = 2; j < 8; ++j) xa[j] = 0.0f;
    }
    split8p(xa, ah, al);
}

// pass A: input proj -> mlp20 (2 tiles/wave) -> segment-sum (uniform-id fast path)
__global__ __launch_bounds__(128, 4) void pass_a(
    const float* __restrict__ md, const float* __restrict__ iobs,
    const float* __restrict__ sig, const float* __restrict__ bimg,
    const char* __restrict__ wsb, const float* __restrict__ b1,
    const float* __restrict__ b2, const int* __restrict__ ids,
    float* __restrict__ sums) {
    __shared__ float smat[2][2][64 * NSTR];
    int lane = threadIdx.x & 63, w = threadIdx.x >> 6;
    int q = lane >> 4, c = lane & 15;
    int i0 = (blockIdx.x * 2 + w) * 32;
    float* smw0 = &smat[w][0][0];
    float* smw1 = &smat[w][1][0];

    bf16x8 ah0, al0, ah1, al1;
    load_xfrag(md, iobs, sig, i0, q, c, ah0, al0);
    load_xfrag(md, iobs, sig, i0 + 16, q, c, ah1, al1);

    float hC0[8], hC1[8];
    input_proj(ah0, al0, (const short*)(wsb + OFF_WIH), (const short*)(wsb + OFF_WIL),
               bimg, hC0, lane, c);
    input_proj(ah1, al1, (const short*)(wsb + OFF_WIH), (const short*)(wsb + OFF_WIL),
               bimg, hC1, lane, c);

    mlp20_x2(hC0, hC1, smw0, smw1,
             (const short*)(wsb + OFF_W1H), (const short*)(wsb + OFF_W1L),
             (const short*)(wsb + OFF_W2H), (const short*)(wsb + OFF_W2L),
             b1, b2, lane, q, c);

#pragma unroll
    for (int tile = 0; tile < 2; ++tile) {
        const float* hC = tile ? hC1 : hC0;
        int tb = i0 + tile * 16;
        bool uni = (ids[tb] == ids[tb + 15]);   // wave-uniform branch
        if (uni) {
            int id = ids[tb];
#pragma unroll
            for (int t = 0; t < 2; ++t) {
                float s = (hC[t * 4 + 0] + hC[t * 4 + 1]) + (hC[t * 4 + 2] + hC[t * 4 + 3]);
                s += __shfl_xor(s, 16, 64);
                s += __shfl_xor(s, 32, 64);
                if (q == 0) atomicAdd(&sums[id * 32 + 16 * t + c], s);
            }
        } else {
            int idv[4];
#pragma unroll
            for (int r = 0; r < 4; ++r) idv[r] = ids[tb + q * 4 + r];
#pragma unroll
            for (int t = 0; t < 2; ++t)
#pragma unroll
                for (int r = 0; r < 4; ++r)
                    atomicAdd(&sums[idv[r] * 32 + 16 * t + c], hC[t * 4 + r]);
        }
    }
}

__global__ __launch_bounds__(256) void normalize_kernel(float* __restrict__ sums,
                                                        const int* __restrict__ cnts) {
    int t = blockIdx.x * 256 + threadIdx.x;
    if (t < NIMG * WIDTH) {
        int img = t >> 5;
        float cc = (float)max(cnts[img], 1);
        sums[t] = sums[t] / cc;
    }
}

// pass B: input proj + pooled -> mlp20 (2 tiles/wave) -> head -> sample -> z, kl
__global__ __launch_bounds__(128, 4) void pass_b(
    const float* __restrict__ md, const float* __restrict__ bsc,
    const char* __restrict__ wsb, const float* __restrict__ b1,
    const float* __restrict__ b2, const float* __restrict__ wout,
    const float* __restrict__ bout, const int* __restrict__ ids,
    const float* __restrict__ pooled, float* __restrict__ out) {
    __shared__ float smat[2][2][64 * NSTR];
    __shared__ float sls[2][64];
    int lane = threadIdx.x & 63, w = threadIdx.x >> 6;
    int q = lane >> 4, c = lane & 15;
    int i0 = (blockIdx.x * 2 + w) * 32;
    float* smw0 = &smat[w][0][0];
    float* smw1 = &smat[w][1][0];

    bf16x8 ah0, al0, ah1, al1;
    load_xfrag(md, nullptr, nullptr, i0, q, c, ah0, al0);
    load_xfrag(md, nullptr, nullptr, i0 + 16, q, c, ah1, al1);

    float hC0[8], hC1[8];
    input_proj(ah0, al0, (const short*)(wsb + OFF_WSH), (const short*)(wsb + OFF_WSL),
               bsc, hC0, lane, c);
    input_proj(ah1, al1, (const short*)(wsb + OFF_WSH), (const short*)(wsb + OFF_WSL),
               bsc, hC1, lane, c);
    // add pooled[id] per row
#pragma unroll
    for (int tile = 0; tile < 2; ++tile) {
        float* hC = tile ? hC1 : hC0;
        int tb = i0 + tile * 16;
        int idv[4];
#pragma unroll
        for (int r = 0; r < 4; ++r) idv[r] = ids[tb + q * 4 + r];
#pragma unroll
        for (int t = 0; t < 2; ++t)
#pragma unroll
            for (int r = 0; r < 4; ++r)
                hC[t * 4 + r] += pooled[idv[r] * 32 + 16 * t + c];
    }

    mlp20_x2(hC0, hC1, smw0, smw1,
             (const short*)(wsb + OFF_W1H), (const short*)(wsb + OFF_W1L),
             (const short*)(wsb + OFF_W2H), (const short*)(wsb + OFF_W2L),
             b1, b2, lane, q, c);

    // head per tile: params = h @ wout + bout (reduce across the 16 c-lanes)
    float wo0[2], wo1[2];
#pragma unroll
    for (int t = 0; t < 2; ++t) {
        float2 wv = ((const float2*)wout)[16 * t + c];
        wo0[t] = wv.x; wo1[t] = wv.y;
    }
#pragma unroll
    for (int tile = 0; tile < 2; ++tile) {
        const float* hC = tile ? hC1 : hC0;
        float p0r[4], p1r[4];
#pragma unroll
        for (int r = 0; r < 4; ++r) {
            p0r[r] = hC[r] * wo0[0] + hC[4 + r] * wo0[1];
            p1r[r] = hC[r] * wo1[0] + hC[4 + r] * wo1[1];
        }
#pragma unroll
        for (int m = 1; m < 16; m <<= 1) {
#pragma unroll
            for (int r = 0; r < 4; ++r) {
                p0r[r] += __shfl_xor(p0r[r], m, 64);
                p1r[r] += __shfl_xor(p1r[r], m, 64);
            }
        }
        if (c == 0) {
#pragma unroll
            for (int r = 0; r < 4; ++r) {
                float loc = p0r[r] + bout[0];
                float pb = p1r[r] + bout[1];
                float scale = fmaxf(pb, 0.0f) + log1pf(expf(-fabsf(pb))) + 1e-12f;
                sls[w][tile * 16 + q * 4 + r] = loc;
                sls[w][32 + tile * 16 + q * 4 + r] = scale;
            }
        }
    }

    // sampling: lane covers row (i0 + lane&31), draws half*16..+15
    int ro = lane & 31, half = lane >> 5;
    int row = i0 + ro;
    float L = sls[w][ro];
    float S = sls[w][32 + ro];
    float lsg = logf(S);
    float kp = 0.0f;
    float* zrow = out + (size_t)row * MC + half * 16;
#pragma unroll 4
    for (int s4 = 0; s4 < 4; ++s4) {
        f32x4 zv;
#pragma unroll
        for (int jj = 0; jj < 4; ++jj) {
            int t = half * 16 + s4 * 4 + jj;
            uint32_t j = (uint32_t)(t * N_ROWS) + (uint32_t)row;
            float n = bits_to_normal(tf_bits(j));
            float z = fmaf(S, n, L);
            zv[jj] = z;
            kp += fmaf(-0.5f, n * n, fabsf(z));
        }
        *(f32x4*)(zrow + s4 * 4) = zv;
    }
    kp += __shfl_xor(kp, 32, 64);
    if (half == 0) {
        out[(size_t)N_ROWS * MC + row] =
            0.01f * (kp * (1.0f / 32.0f) - lsg - 0.91893853320467274f + 0.69314718055994531f);
    }
}

extern "C" void kernel_launch(void* const* d_in, const int* in_sizes, int n_in,
                              void* d_out, int out_size, void* d_ws, size_t ws_size,
                              hipStream_t stream) {
    const float* md   = (const float*)d_in[0];
    const float* iobs = (const float*)d_in[1];
    const float* sig  = (const float*)d_in[2];
    const float* wimg = (const float*)d_in[3];
    const float* bimg = (const float*)d_in[4];
    const float* wsc  = (const float*)d_in[5];
    const float* bsc  = (const float*)d_in[6];
    const float* w1   = (const float*)d_in[7];
    const float* b1   = (const float*)d_in[8];
    const float* w2   = (const float*)d_in[9];
    const float* b2   = (const float*)d_in[10];
    const float* wout = (const float*)d_in[11];
    const float* bout = (const float*)d_in[12];
    const int* ids    = (const int*)d_in[13];
    const int* cnts   = (const int*)d_in[14];
    float* out = (float*)d_out;
    char* wsb = (char*)d_ws;
    float* sums = (float*)wsb;

    const int nblk = N_ROWS / 64;  // 3125 blocks x 2 waves x 32 rows, exact
    prep_kernel<<<391, 256, 0, stream>>>(w1, w2, wimg, wsc, wsb);
    pass_a<<<nblk, 128, 0, stream>>>(md, iobs, sig, bimg, wsb, b1, b2, ids, sums);
    normalize_kernel<<<(NIMG * WIDTH + 255) / 256, 256, 0, stream>>>(sums, cnts);
    pass_b<<<nblk, 128, 0, stream>>>(md, bsc, wsb, b1, b2, wout, bout, ids, sums, out);
}